// Round 14
// baseline (604.079 us; speedup 1.0000x reference)
//
#include <hip/hip_runtime.h>
#include <math.h>

// Problem constants (fixed by setup_inputs: B=8, n=256, s=256)
#define NCTRL 256          // control points
#define NA    259          // n + 3 (TPS system size)
#define NAUG  261          // + 2 rhs columns
#define APITCH 264         // padded row pitch (floats) for the augmented matrix
#define BATCH 8
#define SGRID 256
#define NB    32           // LU panel width
#define NPAN  9            // 8 full panels + 1 of width 3
#define PPITCH 36          // LDS row pitch: 36*4=144B, 16B-aligned rows
#define NT    512          // update/panel block threads (8 waves)
#define PY    4            // eval pixels per thread

// ---------------------------------------------------------------------------
// Kernel 1: build the augmented TPS system. 13 row-strips per batch.
// ---------------------------------------------------------------------------
__global__ __launch_bounds__(256) void build_kernel(const float* __restrict__ src,
                                                    const float* __restrict__ dst,
                                                    float* __restrict__ A){
  const int b = blockIdx.x / 13;
  const int s = blockIdx.x - b*13;
  const int r0 = s*20;
  const int r1 = (r0 + 20 < NA) ? r0 + 20 : NA;
  const float* sb = src + b*NCTRL*2;
  const float* db = dst + b*NCTRL*2;
  float* Ab = A + (size_t)b*NA*APITCH;
  __shared__ float sx[NCTRL], sy[NCTRL];
  {
    int t = threadIdx.x;
    float2 v = ((const float2*)sb)[t];
    sx[t] = v.x; sy[t] = v.y;
  }
  __syncthreads();
  const int total = (r1 - r0)*APITCH;
  for (int idx = threadIdx.x; idx < total; idx += 256){
    int r = r0 + idx / APITCH;
    int c = idx % APITCH;
    float v = 0.0f;
    if (r < NCTRL){
      if (c < NCTRL){
        float dx = sx[r] - sx[c];
        float dy = sy[r] - sy[c];
        v = __builtin_amdgcn_sqrtf(fmaf(dx, dx, dy*dy));
      } else if (c == NCTRL)   v = 1.0f;
      else if (c == NCTRL+1)   v = sx[r];
      else if (c == NCTRL+2)   v = sy[r];
      else if (c == NA)        v = db[2*r];
      else if (c == NA+1)      v = db[2*r+1];
    } else if (c < NCTRL){
      v = (r == NCTRL) ? 1.0f : ((r == NCTRL+1) ? sx[c] : sy[c]);
    }
    Ab[(size_t)r*APITCH + c] = v;
  }
}

// ---------------------------------------------------------------------------
// Flat shift-register panel engine (r11/r13-proven, logic byte-identical —
// only NW is now a wider instantiation). Thread tid owns row tid in rr[] with
// ALL-STATIC register indexing: each ministep consumes column 0 and shifts.
// ONE barrier per ministep.
// ---------------------------------------------------------------------------
template<int NBC, int NW>
__device__ __forceinline__ void flat_engine(
    float (&rr)[NBC], const int rows, const int nb, const int width,
    const int tid, const int lane, const int wid, const int nthreads,
    float (*panout)[PPITCH], float (*ftmp)[PPITCH], int* permout,
    float (*redrow)[NW][PPITCH], float (*redv)[NW], int (*redi)[NW],
    int* scanw)
{
  bool chosen = false;
  int chosenstep = 0;
  for (int j = 0; j < nb; ++j){
    const int par = j & 1;
    const bool active = (tid < rows) && !chosen;
    // wave argmax on current column (= shifted position 0)
    float bv = active ? fabsf(rr[0]) : -1.0f;
    int bi = tid;
    #pragma unroll
    for (int off = 32; off; off >>= 1){
      float ov = __shfl_xor(bv, off);
      int   oi = __shfl_xor(bi, off);
      if (ov > bv || (ov == bv && oi < bi)){ bv = ov; bi = oi; }
    }
    if (tid == bi){                        // per-wave winner publishes
      redv[par][wid] = bv; redi[par][wid] = bi;
      #pragma unroll
      for (int q = 0; q < NBC/4; ++q){
        float4 v; v.x=rr[4*q]; v.y=rr[4*q+1]; v.z=rr[4*q+2]; v.w=rr[4*q+3];
        *(float4*)&redrow[par][wid][4*q] = v;
      }
    }
    __syncthreads();
    // global winner among NW wave candidates
    float gv = redv[par][0]; int gw = 0;
    #pragma unroll
    for (int w = 1; w < NW; ++w){
      if (redv[par][w] > gv ||
          (redv[par][w] == gv && redi[par][w] < redi[par][gw])){
        gv = redv[par][w]; gw = w;
      }
    }
    const int gbi = redi[par][gw];
    // pivot row -> registers (broadcast b128 reads)
    float pr[NBC];
    #pragma unroll
    for (int q = 0; q < NBC/4; ++q){
      float4 v = *(const float4*)&redrow[par][gw][4*q];
      pr[4*q]=v.x; pr[4*q+1]=v.y; pr[4*q+2]=v.z; pr[4*q+3]=v.w;
    }
    // capture U row j (cols j..width-1) from the publish buffer
    if (tid < width - j) panout[j][j + tid] = redrow[par][gw][tid];
    if (tid == gbi){ chosen = true; chosenstep = j; }
    // update + shift, all in registers (static indices)
    if (active && tid != gbi){
      const float rpiv = 1.0f / pr[0];
      const float f = rr[0] * rpiv;
      ftmp[tid][j] = f;                    // L factor by ORIGINAL row
      #pragma unroll
      for (int c = 0; c < NBC-1; ++c)
        rr[c] = fmaf(-f, pr[c+1], rr[c+1]);
    }
  }
  // final positions: chosen -> its step; unchosen -> nb + rank (orig order)
  {
    int x = (tid < rows && !chosen) ? 1 : 0;
    int sPS = x;
    #pragma unroll
    for (int off = 1; off < 64; off <<= 1){
      int o = __shfl_up(sPS, off);
      if (lane >= off) sPS += o;
    }
    if (lane == 63) scanw[wid] = sPS;
    __syncthreads();
    int base = 0;
    for (int w = 0; w < wid; ++w) base += scanw[w];
    if (tid < rows){
      const int newloc = chosen ? chosenstep : (nb + base + sPS - x);
      permout[newloc] = tid;
      const int lim = chosen ? chosenstep : nb;
      for (int c = 0; c < lim; ++c) panout[newloc][c] = ftmp[tid][c];
    }
  }
  __syncthreads();
}

// ---------------------------------------------------------------------------
// Kernel 2: panel 0 (engine only). 512 threads.
// ---------------------------------------------------------------------------
__global__ __launch_bounds__(NT) void panel0_kernel(float* __restrict__ A,
                                                    int* __restrict__ permbuf){
  const int b = blockIdx.x;
  float* Ab = A + (size_t)b*NA*APITCH;
  const int tid = threadIdx.x, lane = tid & 63, wid = tid >> 6;

  __shared__ float pan[NA][PPITCH];
  __shared__ float ftmp[NA][PPITCH];
  __shared__ int   perm[NA];
  __shared__ float redrow[2][8][PPITCH];
  __shared__ float redv[2][8];
  __shared__ int   redi[2][8], scanw[8];

  for (int idx = tid; idx < NA*8; idx += NT){
    int i = idx >> 3, q = idx & 7;
    *(float4*)&pan[i][4*q] = *(const float4*)(Ab + (size_t)i*APITCH + 4*q);
  }
  __syncthreads();

  float rr[NB];
  if (tid < NA){
    #pragma unroll
    for (int q = 0; q < 8; ++q){
      float4 v = *(const float4*)&pan[tid][4*q];
      rr[4*q]=v.x; rr[4*q+1]=v.y; rr[4*q+2]=v.z; rr[4*q+3]=v.w;
    }
  } else {
    #pragma unroll
    for (int c = 0; c < NB; ++c) rr[c] = 0.0f;
  }
  __syncthreads();                        // rr loaded before pan is overwritten

  flat_engine<NB,8>(rr, NA, NB, NB, tid, lane, wid, NT,
                    pan, ftmp, perm, redrow, redv, redi, scanw);

  for (int i = tid; i < NA; i += NT) permbuf[b*(NPAN*NA) + i] = perm[i];
  for (int idx = tid; idx < NA*8; idx += NT){
    int i = idx >> 3, q = idx & 7;
    *(float4*)(Ab + (size_t)i*APITCH + 4*q) = *(const float4*)&pan[i][4*q];
  }
}

// ---------------------------------------------------------------------------
// Kernel 3: trailing update for panel p, one block per 32-col strip, 512 thr.
// XCD-aligned mapping: b = blockIdx & 7 — all strips of a batch share an XCD
// so the panel stays L2-resident (T1). Strip 0 factorizes the NEXT panel.
// ---------------------------------------------------------------------------
template<bool LOOK, int NBCN>
__global__ __launch_bounds__(NT) void update_kernel(float* __restrict__ A,
                                                    int* __restrict__ permbuf,
                                                    int k0, int pidx, int sb,
                                                    int nbn, int wdn, int wbw){
  const int rows = NA - k0;
  const int ctop = k0 + NB;
  const int tc   = NAUG - ctop;
  const int b    = blockIdx.x & 7;       // XCD-aligned: batch -> one XCD
  const int s    = blockIdx.x >> 3;
  const int c0   = s*32;
  const int W    = (tc - c0 < 32) ? (tc - c0) : 32;
  float* Ab = A + (size_t)b*NA*APITCH;
  const int tid  = threadIdx.x;
  const int lane = tid & 63;
  const int wid  = tid >> 6;             // 0..7

  __shared__ float pan[NA][PPITCH];      // factored panel; engine output later
  __shared__ float stage[NA][PPITCH];    // permuted strip; engine ftmp later
  __shared__ float ustg[NB][PPITCH];     // U12 strip
  __shared__ int   perm[NA];
  __shared__ float redrow[2][8][PPITCH];
  __shared__ float redv[2][8];
  __shared__ int   redi[2][8], scanw[8];

  for (int i = tid; i < rows; i += NT)
    perm[i] = permbuf[b*(NPAN*NA) + pidx*NA + i];
  for (int idx = tid; idx < rows*8; idx += NT){
    int i = idx >> 3, q = idx & 7;
    *(float4*)&pan[i][4*q] =
      *(const float4*)(Ab + (size_t)(k0+i)*APITCH + k0 + 4*q);
  }
  __syncthreads();

  // laswp gather: stage[i][c] = A[k0+perm[i]][ctop+c0+c]
  for (int idx = tid; idx < rows*W; idx += NT){
    int i = idx / W, c = idx - i*W;
    stage[i][c] = Ab[(size_t)(k0+perm[i])*APITCH + ctop + c0 + c];
  }
  __syncthreads();

  // TRSM: U12 = L11^{-1} A12, thread-per-column from LDS
  if (tid < W){
    float u[NB];
    #pragma unroll
    for (int m = 0; m < NB; ++m) u[m] = stage[m][tid];
    #pragma unroll
    for (int m = 0; m < NB; ++m){
      #pragma unroll
      for (int jj = m+1; jj < NB; ++jj)
        u[jj] = fmaf(-pan[jj][m], u[m], u[jj]);
    }
    #pragma unroll
    for (int m = 0; m < NB; ++m){
      ustg[m][tid] = u[m];
      Ab[(size_t)(k0+m)*APITCH + ctop + c0 + tid] = u[m];
    }
  }
  __syncthreads();

  // GEMM: A22 -= L21 * U12 (4x4 register tiles)
  const int R = rows - NB;
  if (R > 0){
    const int rt = (R + 3) >> 2, ct = (W + 3) >> 2;
    for (int t = tid; t < rt*ct; t += NT){
      int tr = t / ct, tcc = t - tr*ct;
      int i0 = tr*4, cc0 = tcc*4;
      const bool full = (cc0 + 4 <= W);
      int ir[4];
      #pragma unroll
      for (int r = 0; r < 4; ++r){
        int i = i0 + r;
        ir[r] = (i < R) ? i : (R - 1);
      }
      float acc[4][4];
      #pragma unroll
      for (int r = 0; r < 4; ++r){
        if (full){
          float4 v = *(const float4*)&stage[NB + ir[r]][cc0];
          acc[r][0]=v.x; acc[r][1]=v.y; acc[r][2]=v.z; acc[r][3]=v.w;
        } else {
          #pragma unroll
          for (int c = 0; c < 4; ++c)
            acc[r][c] = (cc0 + c < W) ? stage[NB + ir[r]][cc0 + c] : 0.0f;
        }
      }
      #pragma unroll
      for (int mq = 0; mq < NB/4; ++mq){
        float4 lv[4];
        #pragma unroll
        for (int r = 0; r < 4; ++r)
          lv[r] = *(const float4*)&pan[NB + ir[r]][4*mq];
        #pragma unroll
        for (int mi = 0; mi < 4; ++mi){
          float4 uv = *(const float4*)&ustg[4*mq + mi][cc0];
          #pragma unroll
          for (int r = 0; r < 4; ++r){
            float l = (mi==0) ? lv[r].x : (mi==1) ? lv[r].y : (mi==2) ? lv[r].z : lv[r].w;
            acc[r][0] = fmaf(-l, uv.x, acc[r][0]);
            acc[r][1] = fmaf(-l, uv.y, acc[r][1]);
            acc[r][2] = fmaf(-l, uv.z, acc[r][2]);
            acc[r][3] = fmaf(-l, uv.w, acc[r][3]);
          }
        }
      }
      #pragma unroll
      for (int r = 0; r < 4; ++r){
        if (i0 + r < R){
          float* g = Ab + (size_t)(k0 + NB + i0 + r)*APITCH + ctop + c0 + cc0;
          if (full){
            float4 v; v.x=acc[r][0]; v.y=acc[r][1]; v.z=acc[r][2]; v.w=acc[r][3];
            *(float4*)g = v;
            if (LOOK && s == 0) *(float4*)&stage[NB + i0 + r][cc0] = v;
          } else {
            #pragma unroll
            for (int c = 0; c < 4; ++c)
              if (cc0 + c < W){
                g[c] = acc[r][c];
                if (LOOK && s == 0) stage[NB + i0 + r][cc0 + c] = acc[r][c];
              }
          }
        }
      }
    }
  }

  // lookahead: factor the NEXT panel from LDS (strip 0 only)
  if (LOOK && s == 0){
    __syncthreads();
    const int k0n   = k0 + NB;
    const int rowsN = rows - NB;          // <= 227
    float rr[NBCN];
    if (tid < rowsN){
      #pragma unroll
      for (int q = 0; q < NBCN/4; ++q){
        float4 v = *(const float4*)&stage[NB + tid][4*q];
        rr[4*q]=v.x; rr[4*q+1]=v.y; rr[4*q+2]=v.z; rr[4*q+3]=v.w;
      }
    } else {
      #pragma unroll
      for (int c = 0; c < NBCN; ++c) rr[c] = 0.0f;
    }
    __syncthreads();                      // rr loaded; stage reusable as ftmp

    flat_engine<NBCN,8>(rr, rowsN, nbn, wdn, tid, lane, wid, NT,
                        pan, stage, perm, redrow, redv, redi, scanw);

    for (int i = tid; i < rowsN; i += NT)
      permbuf[b*(NPAN*NA) + (pidx+1)*NA + i] = perm[i];
    if (wbw == NB){
      for (int idx = tid; idx < rowsN*8; idx += NT){
        int i = idx >> 3, q = idx & 7;
        *(float4*)(Ab + (size_t)(k0n+i)*APITCH + k0n + 4*q) =
          *(const float4*)&pan[i][4*q];
      }
    } else {
      for (int idx = tid; idx < rowsN*wbw; idx += NT){
        int i = idx / wbw, c = idx - i*wbw;
        Ab[(size_t)(k0n+i)*APITCH + k0n + c] = pan[i][c];
      }
    }
  }
}

// ---------------------------------------------------------------------------
// Kernel 4: back-substitution (r7-proven right-looking version).
// ---------------------------------------------------------------------------
__global__ __launch_bounds__(512) void backsub_kernel(const float* __restrict__ A,
                                                      float* __restrict__ wv){
  const int b = blockIdx.x;
  const float* Ab = A + (size_t)b*NA*APITCH;
  const int tid  = threadIdx.x;
  const int lane = tid & 63;
  const int wid  = tid >> 6;

  __shared__ float t2[NA][2];
  __shared__ float xs[NA][2];
  __shared__ float u11[NB][NB+1];

  for (int i = tid; i < NA; i += 512){
    t2[i][0] = Ab[(size_t)i*APITCH + NA];
    t2[i][1] = Ab[(size_t)i*APITCH + NA + 1];
  }
  __syncthreads();

  for (int bp = NPAN-1; bp >= 0; --bp){
    const int k0 = bp*NB;
    const int nb = (NA - k0 < NB) ? (NA - k0) : NB;

    for (int idx = tid; idx < nb*nb; idx += 512){
      int r = idx / nb, c = idx - r*nb;
      u11[r][c] = Ab[(size_t)(k0+r)*APITCH + k0 + c];
    }
    __syncthreads();

    if (wid == 0){
      int j = lane >> 1, ch = lane & 1;
      float tval = (j < nb) ? t2[k0+j][ch] : 0.0f;
      for (int k = nb-1; k >= 0; --k){
        float tk = __shfl(tval, 2*k + ch);
        float xk = tk / u11[k][k];
        if (j <  k) tval = fmaf(-u11[j][k], xk, tval);
        if (j == k) tval = xk;
      }
      if (j < nb) xs[k0+j][ch] = tval;
    }
    __syncthreads();

    if (nb == NB){
      const int q = tid & 7;
      for (int base = 0; base < k0; base += 64){
        const int i = base + (tid >> 3);
        float px = 0.0f, py = 0.0f;
        if (i < k0){
          float4 v = *(const float4*)(Ab + (size_t)i*APITCH + k0 + 4*q);
          px = v.x*xs[k0+4*q+0][0] + v.y*xs[k0+4*q+1][0]
             + v.z*xs[k0+4*q+2][0] + v.w*xs[k0+4*q+3][0];
          py = v.x*xs[k0+4*q+0][1] + v.y*xs[k0+4*q+1][1]
             + v.z*xs[k0+4*q+2][1] + v.w*xs[k0+4*q+3][1];
        }
        px += __shfl_xor(px, 1); px += __shfl_xor(px, 2); px += __shfl_xor(px, 4);
        py += __shfl_xor(py, 1); py += __shfl_xor(py, 2); py += __shfl_xor(py, 4);
        if (q == 0 && i < k0){
          t2[i][0] -= px;
          t2[i][1] -= py;
        }
      }
    } else {
      for (int i = tid; i < k0; i += 512){
        float s0 = 0.0f, s1 = 0.0f;
        #pragma unroll
        for (int m = 0; m < 3; ++m){
          float u = Ab[(size_t)i*APITCH + k0 + m];
          s0 = fmaf(u, xs[k0+m][0], s0);
          s1 = fmaf(u, xs[k0+m][1], s1);
        }
        t2[i][0] -= s0;
        t2[i][1] -= s1;
      }
    }
    __syncthreads();
  }

  for (int i = tid; i < NA; i += 512){
    wv[((size_t)b*NA + i)*2 + 0] = xs[i][0];
    wv[((size_t)b*NA + i)*2 + 1] = xs[i][1];
  }
}

// ---------------------------------------------------------------------------
// Kernel 5: evaluate the warp (r10-proven: PY=4, v_sqrt_f32, float4 LDS).
// ---------------------------------------------------------------------------
__global__ __launch_bounds__(256) void eval_kernel(const float* __restrict__ src,
                                                   const float* __restrict__ wv,
                                                   float* __restrict__ out){
  const int b  = blockIdx.x >> 6;          // 8 batches x 64 y-groups
  const int yg = blockIdx.x & 63;
  const int xi = threadIdx.x;
  __shared__ float4 cw[NCTRL];             // (sx, sy, wx, wy)
  const float* sb = src + b*NCTRL*2;
  const float* wb = wv + (size_t)b*NA*2;
  {
    float2 sv = ((const float2*)sb)[xi];
    float2 wv2 = ((const float2*)wb)[xi];
    cw[xi] = make_float4(sv.x, sv.y, wv2.x, wv2.y);
  }
  __syncthreads();

  const float step = 2.0f/255.0f;
  const float gx = -1.0f + step*(float)xi;
  const float w0x = wb[512], w1x = wb[514], w2x = wb[516];
  const float w0y = wb[513], w1y = wb[515], w2y = wb[517];

  float gy[PY], ax[PY], ay[PY];
  #pragma unroll
  for (int p = 0; p < PY; ++p){
    gy[p] = -1.0f + step*(float)(yg*PY + p);
    ax[p] = w0x + w1x*gx + w2x*gy[p];
    ay[p] = w0y + w1y*gx + w2y*gy[p];
  }

  #pragma unroll 4
  for (int j = 0; j < NCTRL; ++j){
    float4 c = cw[j];
    float dx = gx - c.x;
    float dx2 = dx*dx;
    #pragma unroll
    for (int p = 0; p < PY; ++p){
      float dy = gy[p] - c.y;
      float r = __builtin_amdgcn_sqrtf(fmaf(dy, dy, dx2));
      ax[p] = fmaf(r, c.z, ax[p]);
      ay[p] = fmaf(r, c.w, ay[p]);
    }
  }

  const int y0 = yg*PY;
  #pragma unroll
  for (int p = 0; p < PY; ++p){
    out[((size_t)(b*2    )*SGRID + y0 + p)*SGRID + xi] = ax[p];
    out[((size_t)(b*2 + 1)*SGRID + y0 + p)*SGRID + xi] = ay[p];
  }
}

// ---------------------------------------------------------------------------
extern "C" void kernel_launch(void* const* d_in, const int* in_sizes, int n_in,
                              void* d_out, int out_size, void* d_ws, size_t ws_size,
                              hipStream_t stream) {
  const float* src = (const float*)d_in[0];
  const float* dst = (const float*)d_in[1];
  float* out = (float*)d_out;

  const size_t matElems = (size_t)BATCH*NA*APITCH;
  float* A     = (float*)d_ws;
  float* wv    = A + matElems;
  int*   permb = (int*)(wv + (size_t)BATCH*NA*2);

  build_kernel<<<BATCH*13, 256, 0, stream>>>(src, dst, A);
  panel0_kernel<<<BATCH, NT, 0, stream>>>(A, permb);

  // p = 0..6: update + lookahead of panel p+1 (width 32)
  for (int p = 0; p <= 6; ++p){
    const int k0 = p*NB;
    const int tc = NAUG - (k0 + NB);
    const int sb = (tc + 31) >> 5;
    update_kernel<true, NB><<<BATCH*sb, NT, 0, stream>>>(A, permb, k0, p, sb,
                                                         NB, NB, NB);
  }
  // p = 7: update (1 strip) + lookahead of the 5-wide tail block
  // (3 panel cols + 2 rhs; engine eliminates rhs via its shift updates)
  update_kernel<true, 8><<<BATCH, NT, 0, stream>>>(A, permb, 7*NB, 7, 1,
                                                   3, 5, 5);

  backsub_kernel<<<BATCH, 512, 0, stream>>>(A, wv);
  eval_kernel<<<BATCH*(SGRID/PY), 256, 0, stream>>>(src, wv, out);
}

// Round 15
// 509.931 us; speedup vs baseline: 1.1846x; 1.1846x over previous
//
#include <hip/hip_runtime.h>
#include <math.h>

// Problem constants (fixed by setup_inputs: B=8, n=256, s=256)
#define NCTRL 256          // control points
#define NA    259          // n + 3 (TPS system size)
#define NAUG  261          // + 2 rhs columns
#define APITCH 264         // padded row pitch (floats) for the augmented matrix
#define BATCH 8
#define SGRID 256
#define NB    32           // LU panel width
#define NPAN  9            // 8 full panels + 1 of width 3
#define PPITCH 36          // LDS row pitch: 36*4=144B, 16B-aligned rows
#define PY    4            // eval pixels per thread

// ---------------------------------------------------------------------------
// Kernel 1: build the augmented TPS system. 13 row-strips per batch.
// ---------------------------------------------------------------------------
__global__ __launch_bounds__(256) void build_kernel(const float* __restrict__ src,
                                                    const float* __restrict__ dst,
                                                    float* __restrict__ A){
  const int b = blockIdx.x / 13;
  const int s = blockIdx.x - b*13;
  const int r0 = s*20;
  const int r1 = (r0 + 20 < NA) ? r0 + 20 : NA;
  const float* sb = src + b*NCTRL*2;
  const float* db = dst + b*NCTRL*2;
  float* Ab = A + (size_t)b*NA*APITCH;
  __shared__ float sx[NCTRL], sy[NCTRL];
  {
    int t = threadIdx.x;
    float2 v = ((const float2*)sb)[t];
    sx[t] = v.x; sy[t] = v.y;
  }
  __syncthreads();
  const int total = (r1 - r0)*APITCH;
  for (int idx = threadIdx.x; idx < total; idx += 256){
    int r = r0 + idx / APITCH;
    int c = idx % APITCH;
    float v = 0.0f;
    if (r < NCTRL){
      if (c < NCTRL){
        float dx = sx[r] - sx[c];
        float dy = sy[r] - sy[c];
        v = __builtin_amdgcn_sqrtf(fmaf(dx, dx, dy*dy));
      } else if (c == NCTRL)   v = 1.0f;
      else if (c == NCTRL+1)   v = sx[r];
      else if (c == NCTRL+2)   v = sy[r];
      else if (c == NA)        v = db[2*r];
      else if (c == NA+1)      v = db[2*r+1];
    } else if (c < NCTRL){
      v = (r == NCTRL) ? 1.0f : ((r == NCTRL+1) ? sx[c] : sy[c]);
    }
    Ab[(size_t)r*APITCH + c] = v;
  }
}

// ---------------------------------------------------------------------------
// Flat shift-register panel engine (r11/r13-proven, byte-identical). Thread
// tid owns row tid in rr[] with ALL-STATIC register indexing: each ministep
// consumes column 0 and shifts. ONE barrier per ministep.
// ---------------------------------------------------------------------------
template<int NBC, int NW>
__device__ __forceinline__ void flat_engine(
    float (&rr)[NBC], const int rows, const int nb, const int width,
    const int tid, const int lane, const int wid,
    float (*panout)[PPITCH], float (*ftmp)[PPITCH], int* permout,
    float (*redrow)[NW][PPITCH], float (*redv)[NW], int (*redi)[NW],
    int* scanw)
{
  bool chosen = false;
  int chosenstep = 0;
  for (int j = 0; j < nb; ++j){
    const int par = j & 1;
    const bool active = (tid < rows) && !chosen;
    // wave argmax on current column (= shifted position 0)
    float bv = active ? fabsf(rr[0]) : -1.0f;
    int bi = tid;
    #pragma unroll
    for (int off = 32; off; off >>= 1){
      float ov = __shfl_xor(bv, off);
      int   oi = __shfl_xor(bi, off);
      if (ov > bv || (ov == bv && oi < bi)){ bv = ov; bi = oi; }
    }
    if (tid == bi){                        // per-wave winner publishes
      redv[par][wid] = bv; redi[par][wid] = bi;
      #pragma unroll
      for (int q = 0; q < NBC/4; ++q){
        float4 v; v.x=rr[4*q]; v.y=rr[4*q+1]; v.z=rr[4*q+2]; v.w=rr[4*q+3];
        *(float4*)&redrow[par][wid][4*q] = v;
      }
    }
    __syncthreads();
    // global winner among NW wave candidates
    float gv = redv[par][0]; int gw = 0;
    #pragma unroll
    for (int w = 1; w < NW; ++w){
      if (redv[par][w] > gv ||
          (redv[par][w] == gv && redi[par][w] < redi[par][gw])){
        gv = redv[par][w]; gw = w;
      }
    }
    const int gbi = redi[par][gw];
    // pivot row -> registers (broadcast b128 reads)
    float pr[NBC];
    #pragma unroll
    for (int q = 0; q < NBC/4; ++q){
      float4 v = *(const float4*)&redrow[par][gw][4*q];
      pr[4*q]=v.x; pr[4*q+1]=v.y; pr[4*q+2]=v.z; pr[4*q+3]=v.w;
    }
    // capture U row j (cols j..width-1) from the publish buffer
    if (tid < width - j) panout[j][j + tid] = redrow[par][gw][tid];
    if (tid == gbi){ chosen = true; chosenstep = j; }
    // update + shift, all in registers (static indices)
    if (active && tid != gbi){
      const float rpiv = 1.0f / pr[0];
      const float f = rr[0] * rpiv;
      ftmp[tid][j] = f;                    // L factor by ORIGINAL row
      #pragma unroll
      for (int c = 0; c < NBC-1; ++c)
        rr[c] = fmaf(-f, pr[c+1], rr[c+1]);
    }
  }
  // final positions: chosen -> its step; unchosen -> nb + rank (orig order)
  {
    int x = (tid < rows && !chosen) ? 1 : 0;
    int sPS = x;
    #pragma unroll
    for (int off = 1; off < 64; off <<= 1){
      int o = __shfl_up(sPS, off);
      if (lane >= off) sPS += o;
    }
    if (lane == 63) scanw[wid] = sPS;
    __syncthreads();
    int base = 0;
    for (int w = 0; w < wid; ++w) base += scanw[w];
    if (tid < rows){
      const int newloc = chosen ? chosenstep : (nb + base + sPS - x);
      permout[newloc] = tid;
      const int lim = chosen ? chosenstep : nb;
      for (int c = 0; c < lim; ++c) panout[newloc][c] = ftmp[tid][c];
    }
  }
  __syncthreads();
}

// ---------------------------------------------------------------------------
// Kernel 2: panel 0 (engine only). 320 threads (r13-proven).
// ---------------------------------------------------------------------------
__global__ __launch_bounds__(320) void panel0_kernel(float* __restrict__ A,
                                                     int* __restrict__ permbuf){
  const int b = blockIdx.x;
  float* Ab = A + (size_t)b*NA*APITCH;
  const int tid = threadIdx.x, lane = tid & 63, wid = tid >> 6;

  __shared__ float pan[NA][PPITCH];
  __shared__ float ftmp[NA][PPITCH];
  __shared__ int   perm[NA];
  __shared__ float redrow[2][5][PPITCH];
  __shared__ float redv[2][5];
  __shared__ int   redi[2][5], scanw[5];

  for (int idx = tid; idx < NA*8; idx += 320){
    int i = idx >> 3, q = idx & 7;
    *(float4*)&pan[i][4*q] = *(const float4*)(Ab + (size_t)i*APITCH + 4*q);
  }
  __syncthreads();

  float rr[NB];
  if (tid < NA){
    #pragma unroll
    for (int q = 0; q < 8; ++q){
      float4 v = *(const float4*)&pan[tid][4*q];
      rr[4*q]=v.x; rr[4*q+1]=v.y; rr[4*q+2]=v.z; rr[4*q+3]=v.w;
    }
  } else {
    #pragma unroll
    for (int c = 0; c < NB; ++c) rr[c] = 0.0f;
  }
  __syncthreads();                        // rr loaded before pan is overwritten

  flat_engine<NB,5>(rr, NA, NB, NB, tid, lane, wid,
                    pan, ftmp, perm, redrow, redv, redi, scanw);

  for (int i = tid; i < NA; i += 320) permbuf[b*(NPAN*NA) + i] = perm[i];
  for (int idx = tid; idx < NA*8; idx += 320){
    int i = idx >> 3, q = idx & 7;
    *(float4*)(Ab + (size_t)i*APITCH + 4*q) = *(const float4*)&pan[i][4*q];
  }
}

// ---------------------------------------------------------------------------
// Kernel 3: trailing update for panel p, one block per 32-col strip (r13,
// 256 threads). ONLY change vs r13: XCD-aligned mapping b = blockIdx & 7 —
// all strips of a batch share an XCD so the panel stays L2-resident (T1;
// FETCH drop verified in r14). Strip 0 factorizes the NEXT panel.
// ---------------------------------------------------------------------------
template<bool LOOK, int NBCN>
__global__ __launch_bounds__(256) void update_kernel(float* __restrict__ A,
                                                     int* __restrict__ permbuf,
                                                     int k0, int pidx, int sb,
                                                     int nbn, int wdn, int wbw){
  const int rows = NA - k0;
  const int ctop = k0 + NB;
  const int tc   = NAUG - ctop;
  const int b    = blockIdx.x & 7;       // XCD-aligned: batch -> one XCD
  const int s    = blockIdx.x >> 3;
  const int c0   = s*32;
  const int W    = (tc - c0 < 32) ? (tc - c0) : 32;
  float* Ab = A + (size_t)b*NA*APITCH;
  const int tid  = threadIdx.x;
  const int lane = tid & 63;
  const int wid  = tid >> 6;             // 0..3

  __shared__ float pan[NA][PPITCH];      // factored panel; engine output later
  __shared__ float stage[NA][PPITCH];    // permuted strip; engine ftmp later
  __shared__ float ustg[NB][PPITCH];     // U12 strip
  __shared__ int   perm[NA];
  __shared__ float redrow[2][4][PPITCH];
  __shared__ float redv[2][4];
  __shared__ int   redi[2][4], scanw[4];

  for (int i = tid; i < rows; i += 256)
    perm[i] = permbuf[b*(NPAN*NA) + pidx*NA + i];
  for (int idx = tid; idx < rows*8; idx += 256){
    int i = idx >> 3, q = idx & 7;
    *(float4*)&pan[i][4*q] =
      *(const float4*)(Ab + (size_t)(k0+i)*APITCH + k0 + 4*q);
  }
  __syncthreads();

  // laswp gather: stage[i][c] = A[k0+perm[i]][ctop+c0+c]
  for (int idx = tid; idx < rows*W; idx += 256){
    int i = idx / W, c = idx - i*W;
    stage[i][c] = Ab[(size_t)(k0+perm[i])*APITCH + ctop + c0 + c];
  }
  __syncthreads();

  // TRSM: U12 = L11^{-1} A12, thread-per-column from LDS
  if (tid < W){
    float u[NB];
    #pragma unroll
    for (int m = 0; m < NB; ++m) u[m] = stage[m][tid];
    #pragma unroll
    for (int m = 0; m < NB; ++m){
      #pragma unroll
      for (int jj = m+1; jj < NB; ++jj)
        u[jj] = fmaf(-pan[jj][m], u[m], u[jj]);
    }
    #pragma unroll
    for (int m = 0; m < NB; ++m){
      ustg[m][tid] = u[m];
      Ab[(size_t)(k0+m)*APITCH + ctop + c0 + tid] = u[m];
    }
  }
  __syncthreads();

  // GEMM: A22 -= L21 * U12 (4x4 register tiles)
  const int R = rows - NB;
  if (R > 0){
    const int rt = (R + 3) >> 2, ct = (W + 3) >> 2;
    for (int t = tid; t < rt*ct; t += 256){
      int tr = t / ct, tcc = t - tr*ct;
      int i0 = tr*4, cc0 = tcc*4;
      const bool full = (cc0 + 4 <= W);
      int ir[4];
      #pragma unroll
      for (int r = 0; r < 4; ++r){
        int i = i0 + r;
        ir[r] = (i < R) ? i : (R - 1);
      }
      float acc[4][4];
      #pragma unroll
      for (int r = 0; r < 4; ++r){
        if (full){
          float4 v = *(const float4*)&stage[NB + ir[r]][cc0];
          acc[r][0]=v.x; acc[r][1]=v.y; acc[r][2]=v.z; acc[r][3]=v.w;
        } else {
          #pragma unroll
          for (int c = 0; c < 4; ++c)
            acc[r][c] = (cc0 + c < W) ? stage[NB + ir[r]][cc0 + c] : 0.0f;
        }
      }
      #pragma unroll
      for (int mq = 0; mq < NB/4; ++mq){
        float4 lv[4];
        #pragma unroll
        for (int r = 0; r < 4; ++r)
          lv[r] = *(const float4*)&pan[NB + ir[r]][4*mq];
        #pragma unroll
        for (int mi = 0; mi < 4; ++mi){
          float4 uv = *(const float4*)&ustg[4*mq + mi][cc0];
          #pragma unroll
          for (int r = 0; r < 4; ++r){
            float l = (mi==0) ? lv[r].x : (mi==1) ? lv[r].y : (mi==2) ? lv[r].z : lv[r].w;
            acc[r][0] = fmaf(-l, uv.x, acc[r][0]);
            acc[r][1] = fmaf(-l, uv.y, acc[r][1]);
            acc[r][2] = fmaf(-l, uv.z, acc[r][2]);
            acc[r][3] = fmaf(-l, uv.w, acc[r][3]);
          }
        }
      }
      #pragma unroll
      for (int r = 0; r < 4; ++r){
        if (i0 + r < R){
          float* g = Ab + (size_t)(k0 + NB + i0 + r)*APITCH + ctop + c0 + cc0;
          if (full){
            float4 v; v.x=acc[r][0]; v.y=acc[r][1]; v.z=acc[r][2]; v.w=acc[r][3];
            *(float4*)g = v;
            if (LOOK && s == 0) *(float4*)&stage[NB + i0 + r][cc0] = v;
          } else {
            #pragma unroll
            for (int c = 0; c < 4; ++c)
              if (cc0 + c < W){
                g[c] = acc[r][c];
                if (LOOK && s == 0) stage[NB + i0 + r][cc0 + c] = acc[r][c];
              }
          }
        }
      }
    }
  }

  // lookahead: factor the NEXT panel from LDS (strip 0 only)
  if (LOOK && s == 0){
    __syncthreads();
    const int k0n   = k0 + NB;
    const int rowsN = rows - NB;          // <= 227 < 256 threads
    float rr[NBCN];
    if (tid < rowsN){
      #pragma unroll
      for (int q = 0; q < NBCN/4; ++q){
        float4 v = *(const float4*)&stage[NB + tid][4*q];
        rr[4*q]=v.x; rr[4*q+1]=v.y; rr[4*q+2]=v.z; rr[4*q+3]=v.w;
      }
    } else {
      #pragma unroll
      for (int c = 0; c < NBCN; ++c) rr[c] = 0.0f;
    }
    __syncthreads();                      // rr loaded; stage reusable as ftmp

    flat_engine<NBCN,4>(rr, rowsN, nbn, wdn, tid, lane, wid,
                        pan, stage, perm, redrow, redv, redi, scanw);

    for (int i = tid; i < rowsN; i += 256)
      permbuf[b*(NPAN*NA) + (pidx+1)*NA + i] = perm[i];
    if (wbw == NB){
      for (int idx = tid; idx < rowsN*8; idx += 256){
        int i = idx >> 3, q = idx & 7;
        *(float4*)(Ab + (size_t)(k0n+i)*APITCH + k0n + 4*q) =
          *(const float4*)&pan[i][4*q];
      }
    } else {
      for (int idx = tid; idx < rowsN*wbw; idx += 256){
        int i = idx / wbw, c = idx - i*wbw;
        Ab[(size_t)(k0n+i)*APITCH + k0n + c] = pan[i][c];
      }
    }
  }
}

// ---------------------------------------------------------------------------
// Kernel 4: back-substitution (r7-proven right-looking version).
// ---------------------------------------------------------------------------
__global__ __launch_bounds__(512) void backsub_kernel(const float* __restrict__ A,
                                                      float* __restrict__ wv){
  const int b = blockIdx.x;
  const float* Ab = A + (size_t)b*NA*APITCH;
  const int tid  = threadIdx.x;
  const int lane = tid & 63;
  const int wid  = tid >> 6;

  __shared__ float t2[NA][2];
  __shared__ float xs[NA][2];
  __shared__ float u11[NB][NB+1];

  for (int i = tid; i < NA; i += 512){
    t2[i][0] = Ab[(size_t)i*APITCH + NA];
    t2[i][1] = Ab[(size_t)i*APITCH + NA + 1];
  }
  __syncthreads();

  for (int bp = NPAN-1; bp >= 0; --bp){
    const int k0 = bp*NB;
    const int nb = (NA - k0 < NB) ? (NA - k0) : NB;

    for (int idx = tid; idx < nb*nb; idx += 512){
      int r = idx / nb, c = idx - r*nb;
      u11[r][c] = Ab[(size_t)(k0+r)*APITCH + k0 + c];
    }
    __syncthreads();

    if (wid == 0){
      int j = lane >> 1, ch = lane & 1;
      float tval = (j < nb) ? t2[k0+j][ch] : 0.0f;
      for (int k = nb-1; k >= 0; --k){
        float tk = __shfl(tval, 2*k + ch);
        float xk = tk / u11[k][k];
        if (j <  k) tval = fmaf(-u11[j][k], xk, tval);
        if (j == k) tval = xk;
      }
      if (j < nb) xs[k0+j][ch] = tval;
    }
    __syncthreads();

    if (nb == NB){
      const int q = tid & 7;
      for (int base = 0; base < k0; base += 64){
        const int i = base + (tid >> 3);
        float px = 0.0f, py = 0.0f;
        if (i < k0){
          float4 v = *(const float4*)(Ab + (size_t)i*APITCH + k0 + 4*q);
          px = v.x*xs[k0+4*q+0][0] + v.y*xs[k0+4*q+1][0]
             + v.z*xs[k0+4*q+2][0] + v.w*xs[k0+4*q+3][0];
          py = v.x*xs[k0+4*q+0][1] + v.y*xs[k0+4*q+1][1]
             + v.z*xs[k0+4*q+2][1] + v.w*xs[k0+4*q+3][1];
        }
        px += __shfl_xor(px, 1); px += __shfl_xor(px, 2); px += __shfl_xor(px, 4);
        py += __shfl_xor(py, 1); py += __shfl_xor(py, 2); py += __shfl_xor(py, 4);
        if (q == 0 && i < k0){
          t2[i][0] -= px;
          t2[i][1] -= py;
        }
      }
    } else {
      for (int i = tid; i < k0; i += 512){
        float s0 = 0.0f, s1 = 0.0f;
        #pragma unroll
        for (int m = 0; m < 3; ++m){
          float u = Ab[(size_t)i*APITCH + k0 + m];
          s0 = fmaf(u, xs[k0+m][0], s0);
          s1 = fmaf(u, xs[k0+m][1], s1);
        }
        t2[i][0] -= s0;
        t2[i][1] -= s1;
      }
    }
    __syncthreads();
  }

  for (int i = tid; i < NA; i += 512){
    wv[((size_t)b*NA + i)*2 + 0] = xs[i][0];
    wv[((size_t)b*NA + i)*2 + 1] = xs[i][1];
  }
}

// ---------------------------------------------------------------------------
// Kernel 5: evaluate the warp (r10-proven: PY=4, v_sqrt_f32, float4 LDS).
// ---------------------------------------------------------------------------
__global__ __launch_bounds__(256) void eval_kernel(const float* __restrict__ src,
                                                   const float* __restrict__ wv,
                                                   float* __restrict__ out){
  const int b  = blockIdx.x >> 6;          // 8 batches x 64 y-groups
  const int yg = blockIdx.x & 63;
  const int xi = threadIdx.x;
  __shared__ float4 cw[NCTRL];             // (sx, sy, wx, wy)
  const float* sb = src + b*NCTRL*2;
  const float* wb = wv + (size_t)b*NA*2;
  {
    float2 sv = ((const float2*)sb)[xi];
    float2 wv2 = ((const float2*)wb)[xi];
    cw[xi] = make_float4(sv.x, sv.y, wv2.x, wv2.y);
  }
  __syncthreads();

  const float step = 2.0f/255.0f;
  const float gx = -1.0f + step*(float)xi;
  const float w0x = wb[512], w1x = wb[514], w2x = wb[516];
  const float w0y = wb[513], w1y = wb[515], w2y = wb[517];

  float gy[PY], ax[PY], ay[PY];
  #pragma unroll
  for (int p = 0; p < PY; ++p){
    gy[p] = -1.0f + step*(float)(yg*PY + p);
    ax[p] = w0x + w1x*gx + w2x*gy[p];
    ay[p] = w0y + w1y*gx + w2y*gy[p];
  }

  #pragma unroll 4
  for (int j = 0; j < NCTRL; ++j){
    float4 c = cw[j];
    float dx = gx - c.x;
    float dx2 = dx*dx;
    #pragma unroll
    for (int p = 0; p < PY; ++p){
      float dy = gy[p] - c.y;
      float r = __builtin_amdgcn_sqrtf(fmaf(dy, dy, dx2));
      ax[p] = fmaf(r, c.z, ax[p]);
      ay[p] = fmaf(r, c.w, ay[p]);
    }
  }

  const int y0 = yg*PY;
  #pragma unroll
  for (int p = 0; p < PY; ++p){
    out[((size_t)(b*2    )*SGRID + y0 + p)*SGRID + xi] = ax[p];
    out[((size_t)(b*2 + 1)*SGRID + y0 + p)*SGRID + xi] = ay[p];
  }
}

// ---------------------------------------------------------------------------
extern "C" void kernel_launch(void* const* d_in, const int* in_sizes, int n_in,
                              void* d_out, int out_size, void* d_ws, size_t ws_size,
                              hipStream_t stream) {
  const float* src = (const float*)d_in[0];
  const float* dst = (const float*)d_in[1];
  float* out = (float*)d_out;

  const size_t matElems = (size_t)BATCH*NA*APITCH;
  float* A     = (float*)d_ws;
  float* wv    = A + matElems;
  int*   permb = (int*)(wv + (size_t)BATCH*NA*2);

  build_kernel<<<BATCH*13, 256, 0, stream>>>(src, dst, A);
  panel0_kernel<<<BATCH, 320, 0, stream>>>(A, permb);

  // p = 0..6: update + lookahead of panel p+1 (width 32)
  for (int p = 0; p <= 6; ++p){
    const int k0 = p*NB;
    const int tc = NAUG - (k0 + NB);
    const int sb = (tc + 31) >> 5;
    update_kernel<true, NB><<<BATCH*sb, 256, 0, stream>>>(A, permb, k0, p, sb,
                                                          NB, NB, NB);
  }
  // p = 7: update (1 strip) + lookahead of the 5-wide tail block
  // (3 panel cols + 2 rhs; engine eliminates rhs via its shift updates)
  update_kernel<true, 8><<<BATCH, 256, 0, stream>>>(A, permb, 7*NB, 7, 1,
                                                    3, 5, 5);

  backsub_kernel<<<BATCH, 512, 0, stream>>>(A, wv);
  eval_kernel<<<BATCH*(SGRID/PY), 256, 0, stream>>>(src, wv, out);
}

// Round 16
// 502.767 us; speedup vs baseline: 1.2015x; 1.0142x over previous
//
#include <hip/hip_runtime.h>
#include <math.h>

// Problem constants (fixed by setup_inputs: B=8, n=256, s=256)
#define NCTRL 256          // control points
#define NA    259          // n + 3 (TPS system size)
#define NAUG  261          // + 2 rhs columns
#define APITCH 264         // padded row pitch (floats) for the augmented matrix
#define BATCH 8
#define SGRID 256
#define NB    32           // LU panel width
#define NPAN  9            // 8 full panels + 1 of width 3
#define PPITCH 36          // LDS row pitch: 36*4=144B, 16B-aligned rows
#define FTP   264          // ftmp pitch (L factors, transposed: [step][row])
#define PY    4            // eval pixels per thread

// ---------------------------------------------------------------------------
// Kernel 1: build the augmented TPS system. 13 row-strips per batch.
// ---------------------------------------------------------------------------
__global__ __launch_bounds__(256) void build_kernel(const float* __restrict__ src,
                                                    const float* __restrict__ dst,
                                                    float* __restrict__ A){
  const int b = blockIdx.x / 13;
  const int s = blockIdx.x - b*13;
  const int r0 = s*20;
  const int r1 = (r0 + 20 < NA) ? r0 + 20 : NA;
  const float* sb = src + b*NCTRL*2;
  const float* db = dst + b*NCTRL*2;
  float* Ab = A + (size_t)b*NA*APITCH;
  __shared__ float sx[NCTRL], sy[NCTRL];
  {
    int t = threadIdx.x;
    float2 v = ((const float2*)sb)[t];
    sx[t] = v.x; sy[t] = v.y;
  }
  __syncthreads();
  const int total = (r1 - r0)*APITCH;
  for (int idx = threadIdx.x; idx < total; idx += 256){
    int r = r0 + idx / APITCH;
    int c = idx % APITCH;
    float v = 0.0f;
    if (r < NCTRL){
      if (c < NCTRL){
        float dx = sx[r] - sx[c];
        float dy = sy[r] - sy[c];
        v = __builtin_amdgcn_sqrtf(fmaf(dx, dx, dy*dy));
      } else if (c == NCTRL)   v = 1.0f;
      else if (c == NCTRL+1)   v = sx[r];
      else if (c == NCTRL+2)   v = sy[r];
      else if (c == NA)        v = db[2*r];
      else if (c == NA+1)      v = db[2*r+1];
    } else if (c < NCTRL){
      v = (r == NCTRL) ? 1.0f : ((r == NCTRL+1) ? sx[c] : sy[c]);
    }
    Ab[(size_t)r*APITCH + c] = v;
  }
}

// ---------------------------------------------------------------------------
// Flat shift-register panel engine (r11/r13-proven core). Round-16 changes:
//  (a) publish/broadcast quads guarded by uniform `4q <= width-1-j` — only
//      live columns move through LDS (dead register slots are never read:
//      live data at step j occupies rr[0..width-1-j], shrinking by 1/step);
//  (b) ftmp transposed to [step][orig_row] pitch FTP — conflict-free stride-1
//      writes (was 8-way bank conflict at pitch 36).
// ONE barrier per ministep; all-static register indexing.
// ---------------------------------------------------------------------------
template<int NBC, int NW>
__device__ __forceinline__ void flat_engine(
    float (&rr)[NBC], const int rows, const int nb, const int width,
    const int tid, const int lane, const int wid,
    float (*panout)[PPITCH], float (*ftmp)[FTP], int* permout,
    float (*redrow)[NW][PPITCH], float (*redv)[NW], int (*redi)[NW],
    int* scanw)
{
  bool chosen = false;
  int chosenstep = 0;
  for (int j = 0; j < nb; ++j){
    const int par = j & 1;
    const int wlim = width - 1 - j;        // highest live (shifted) col index
    const bool active = (tid < rows) && !chosen;
    // wave argmax on current column (= shifted position 0)
    float bv = active ? fabsf(rr[0]) : -1.0f;
    int bi = tid;
    #pragma unroll
    for (int off = 32; off; off >>= 1){
      float ov = __shfl_xor(bv, off);
      int   oi = __shfl_xor(bi, off);
      if (ov > bv || (ov == bv && oi < bi)){ bv = ov; bi = oi; }
    }
    if (tid == bi){                        // per-wave winner publishes (live quads)
      redv[par][wid] = bv; redi[par][wid] = bi;
      #pragma unroll
      for (int q = 0; q < NBC/4; ++q){
        if (4*q <= wlim){
          float4 v; v.x=rr[4*q]; v.y=rr[4*q+1]; v.z=rr[4*q+2]; v.w=rr[4*q+3];
          *(float4*)&redrow[par][wid][4*q] = v;
        }
      }
    }
    __syncthreads();
    // global winner among NW wave candidates
    float gv = redv[par][0]; int gw = 0;
    #pragma unroll
    for (int w = 1; w < NW; ++w){
      if (redv[par][w] > gv ||
          (redv[par][w] == gv && redi[par][w] < redi[par][gw])){
        gv = redv[par][w]; gw = w;
      }
    }
    const int gbi = redi[par][gw];
    // pivot row -> registers (broadcast b128 reads, live quads only)
    float pr[NBC];
    #pragma unroll
    for (int q = 0; q < NBC/4; ++q){
      if (4*q <= wlim){
        float4 v = *(const float4*)&redrow[par][gw][4*q];
        pr[4*q]=v.x; pr[4*q+1]=v.y; pr[4*q+2]=v.z; pr[4*q+3]=v.w;
      }
    }
    // capture U row j (cols j..width-1) from the publish buffer
    if (tid <= wlim) panout[j][j + tid] = redrow[par][gw][tid];
    if (tid == gbi){ chosen = true; chosenstep = j; }
    // update + shift, all in registers (static indices; slots >= wlim dead)
    if (active && tid != gbi){
      const float rpiv = 1.0f / pr[0];
      const float f = rr[0] * rpiv;
      ftmp[j][tid] = f;                    // L factor, stride-1 (conflict-free)
      #pragma unroll
      for (int c = 0; c < NBC-1; ++c)
        rr[c] = fmaf(-f, pr[c+1], rr[c+1]);
    }
  }
  // final positions: chosen -> its step; unchosen -> nb + rank (orig order)
  {
    int x = (tid < rows && !chosen) ? 1 : 0;
    int sPS = x;
    #pragma unroll
    for (int off = 1; off < 64; off <<= 1){
      int o = __shfl_up(sPS, off);
      if (lane >= off) sPS += o;
    }
    if (lane == 63) scanw[wid] = sPS;
    __syncthreads();
    int base = 0;
    for (int w = 0; w < wid; ++w) base += scanw[w];
    if (tid < rows){
      const int newloc = chosen ? chosenstep : (nb + base + sPS - x);
      permout[newloc] = tid;
      const int lim = chosen ? chosenstep : nb;
      for (int c = 0; c < lim; ++c) panout[newloc][c] = ftmp[c][tid];
    }
  }
  __syncthreads();
}

// ---------------------------------------------------------------------------
// Kernel 2: panel 0 (engine only). 320 threads (r13-proven).
// ---------------------------------------------------------------------------
__global__ __launch_bounds__(320) void panel0_kernel(float* __restrict__ A,
                                                     int* __restrict__ permbuf){
  const int b = blockIdx.x;
  float* Ab = A + (size_t)b*NA*APITCH;
  const int tid = threadIdx.x, lane = tid & 63, wid = tid >> 6;

  __shared__ float pan[NA][PPITCH];
  __shared__ float ftmp[NB][FTP];
  __shared__ int   perm[NA];
  __shared__ float redrow[2][5][PPITCH];
  __shared__ float redv[2][5];
  __shared__ int   redi[2][5], scanw[5];

  for (int idx = tid; idx < NA*8; idx += 320){
    int i = idx >> 3, q = idx & 7;
    *(float4*)&pan[i][4*q] = *(const float4*)(Ab + (size_t)i*APITCH + 4*q);
  }
  __syncthreads();

  float rr[NB];
  if (tid < NA){
    #pragma unroll
    for (int q = 0; q < 8; ++q){
      float4 v = *(const float4*)&pan[tid][4*q];
      rr[4*q]=v.x; rr[4*q+1]=v.y; rr[4*q+2]=v.z; rr[4*q+3]=v.w;
    }
  } else {
    #pragma unroll
    for (int c = 0; c < NB; ++c) rr[c] = 0.0f;
  }
  __syncthreads();                        // rr loaded before pan is overwritten

  flat_engine<NB,5>(rr, NA, NB, NB, tid, lane, wid,
                    pan, ftmp, perm, redrow, redv, redi, scanw);

  for (int i = tid; i < NA; i += 320) permbuf[b*(NPAN*NA) + i] = perm[i];
  for (int idx = tid; idx < NA*8; idx += 320){
    int i = idx >> 3, q = idx & 7;
    *(float4*)(Ab + (size_t)i*APITCH + 4*q) = *(const float4*)&pan[i][4*q];
  }
}

// ---------------------------------------------------------------------------
// Kernel 3: trailing update for panel p, one block per 32-col strip.
// XCD-aligned mapping (r15-proven: b = blockIdx & 7). Strip 0 factorizes the
// NEXT panel; its GEMM result skips the (dead) global write — the lookahead
// write-back fully overwrites that region of A.
// ---------------------------------------------------------------------------
template<bool LOOK, int NBCN>
__global__ __launch_bounds__(256) void update_kernel(float* __restrict__ A,
                                                     int* __restrict__ permbuf,
                                                     int k0, int pidx, int sb,
                                                     int nbn, int wdn, int wbw){
  const int rows = NA - k0;
  const int ctop = k0 + NB;
  const int tc   = NAUG - ctop;
  const int b    = blockIdx.x & 7;       // XCD-aligned: batch -> one XCD
  const int s    = blockIdx.x >> 3;
  const int c0   = s*32;
  const int W    = (tc - c0 < 32) ? (tc - c0) : 32;
  float* Ab = A + (size_t)b*NA*APITCH;
  const int tid  = threadIdx.x;
  const int lane = tid & 63;
  const int wid  = tid >> 6;             // 0..3

  __shared__ float pan[NA][PPITCH];      // factored panel; engine output later
  __shared__ float stage[NA][PPITCH];    // permuted strip; engine ftmp later
  __shared__ float ustg[NB][PPITCH];     // U12 strip
  __shared__ int   perm[NA];
  __shared__ float redrow[2][4][PPITCH];
  __shared__ float redv[2][4];
  __shared__ int   redi[2][4], scanw[4];

  for (int i = tid; i < rows; i += 256)
    perm[i] = permbuf[b*(NPAN*NA) + pidx*NA + i];
  for (int idx = tid; idx < rows*8; idx += 256){
    int i = idx >> 3, q = idx & 7;
    *(float4*)&pan[i][4*q] =
      *(const float4*)(Ab + (size_t)(k0+i)*APITCH + k0 + 4*q);
  }
  __syncthreads();

  // laswp gather: stage[i][c] = A[k0+perm[i]][ctop+c0+c]
  for (int idx = tid; idx < rows*W; idx += 256){
    int i = idx / W, c = idx - i*W;
    stage[i][c] = Ab[(size_t)(k0+perm[i])*APITCH + ctop + c0 + c];
  }
  __syncthreads();

  // TRSM: U12 = L11^{-1} A12, thread-per-column from LDS
  if (tid < W){
    float u[NB];
    #pragma unroll
    for (int m = 0; m < NB; ++m) u[m] = stage[m][tid];
    #pragma unroll
    for (int m = 0; m < NB; ++m){
      #pragma unroll
      for (int jj = m+1; jj < NB; ++jj)
        u[jj] = fmaf(-pan[jj][m], u[m], u[jj]);
    }
    #pragma unroll
    for (int m = 0; m < NB; ++m){
      ustg[m][tid] = u[m];
      Ab[(size_t)(k0+m)*APITCH + ctop + c0 + tid] = u[m];
    }
  }
  __syncthreads();

  // GEMM: A22 -= L21 * U12 (4x4 register tiles)
  const int R = rows - NB;
  if (R > 0){
    const int rt = (R + 3) >> 2, ct = (W + 3) >> 2;
    for (int t = tid; t < rt*ct; t += 256){
      int tr = t / ct, tcc = t - tr*ct;
      int i0 = tr*4, cc0 = tcc*4;
      const bool full = (cc0 + 4 <= W);
      int ir[4];
      #pragma unroll
      for (int r = 0; r < 4; ++r){
        int i = i0 + r;
        ir[r] = (i < R) ? i : (R - 1);
      }
      float acc[4][4];
      #pragma unroll
      for (int r = 0; r < 4; ++r){
        if (full){
          float4 v = *(const float4*)&stage[NB + ir[r]][cc0];
          acc[r][0]=v.x; acc[r][1]=v.y; acc[r][2]=v.z; acc[r][3]=v.w;
        } else {
          #pragma unroll
          for (int c = 0; c < 4; ++c)
            acc[r][c] = (cc0 + c < W) ? stage[NB + ir[r]][cc0 + c] : 0.0f;
        }
      }
      #pragma unroll
      for (int mq = 0; mq < NB/4; ++mq){
        float4 lv[4];
        #pragma unroll
        for (int r = 0; r < 4; ++r)
          lv[r] = *(const float4*)&pan[NB + ir[r]][4*mq];
        #pragma unroll
        for (int mi = 0; mi < 4; ++mi){
          float4 uv = *(const float4*)&ustg[4*mq + mi][cc0];
          #pragma unroll
          for (int r = 0; r < 4; ++r){
            float l = (mi==0) ? lv[r].x : (mi==1) ? lv[r].y : (mi==2) ? lv[r].z : lv[r].w;
            acc[r][0] = fmaf(-l, uv.x, acc[r][0]);
            acc[r][1] = fmaf(-l, uv.y, acc[r][1]);
            acc[r][2] = fmaf(-l, uv.z, acc[r][2]);
            acc[r][3] = fmaf(-l, uv.w, acc[r][3]);
          }
        }
      }
      #pragma unroll
      for (int r = 0; r < 4; ++r){
        if (i0 + r < R){
          if (LOOK && s == 0){
            // global write is dead here: lookahead write-back overwrites it
            if (full){
              float4 v; v.x=acc[r][0]; v.y=acc[r][1]; v.z=acc[r][2]; v.w=acc[r][3];
              *(float4*)&stage[NB + i0 + r][cc0] = v;
            } else {
              #pragma unroll
              for (int c = 0; c < 4; ++c)
                if (cc0 + c < W) stage[NB + i0 + r][cc0 + c] = acc[r][c];
            }
          } else {
            float* g = Ab + (size_t)(k0 + NB + i0 + r)*APITCH + ctop + c0 + cc0;
            if (full){
              float4 v; v.x=acc[r][0]; v.y=acc[r][1]; v.z=acc[r][2]; v.w=acc[r][3];
              *(float4*)g = v;
            } else {
              #pragma unroll
              for (int c = 0; c < 4; ++c)
                if (cc0 + c < W) g[c] = acc[r][c];
            }
          }
        }
      }
    }
  }

  // lookahead: factor the NEXT panel from LDS (strip 0 only)
  if (LOOK && s == 0){
    __syncthreads();
    const int k0n   = k0 + NB;
    const int rowsN = rows - NB;          // <= 227 < 256 threads
    float rr[NBCN];
    if (tid < rowsN){
      #pragma unroll
      for (int q = 0; q < NBCN/4; ++q){
        float4 v = *(const float4*)&stage[NB + tid][4*q];
        rr[4*q]=v.x; rr[4*q+1]=v.y; rr[4*q+2]=v.z; rr[4*q+3]=v.w;
      }
    } else {
      #pragma unroll
      for (int c = 0; c < NBCN; ++c) rr[c] = 0.0f;
    }
    __syncthreads();                      // rr loaded; stage reusable as ftmp

    // ftmp (transposed [step][row], pitch FTP) overlays the stage buffer:
    // needs NB*FTP = 8448 floats <= NA*PPITCH = 9324.
    float (*ftmpc)[FTP] = reinterpret_cast<float(*)[FTP]>(&stage[0][0]);
    flat_engine<NBCN,4>(rr, rowsN, nbn, wdn, tid, lane, wid,
                        pan, ftmpc, perm, redrow, redv, redi, scanw);

    for (int i = tid; i < rowsN; i += 256)
      permbuf[b*(NPAN*NA) + (pidx+1)*NA + i] = perm[i];
    if (wbw == NB){
      for (int idx = tid; idx < rowsN*8; idx += 256){
        int i = idx >> 3, q = idx & 7;
        *(float4*)(Ab + (size_t)(k0n+i)*APITCH + k0n + 4*q) =
          *(const float4*)&pan[i][4*q];
      }
    } else {
      for (int idx = tid; idx < rowsN*wbw; idx += 256){
        int i = idx / wbw, c = idx - i*wbw;
        Ab[(size_t)(k0n+i)*APITCH + k0n + c] = pan[i][c];
      }
    }
  }
}

// ---------------------------------------------------------------------------
// Kernel 4: back-substitution (r7-proven right-looking version).
// ---------------------------------------------------------------------------
__global__ __launch_bounds__(512) void backsub_kernel(const float* __restrict__ A,
                                                      float* __restrict__ wv){
  const int b = blockIdx.x;
  const float* Ab = A + (size_t)b*NA*APITCH;
  const int tid  = threadIdx.x;
  const int lane = tid & 63;
  const int wid  = tid >> 6;

  __shared__ float t2[NA][2];
  __shared__ float xs[NA][2];
  __shared__ float u11[NB][NB+1];

  for (int i = tid; i < NA; i += 512){
    t2[i][0] = Ab[(size_t)i*APITCH + NA];
    t2[i][1] = Ab[(size_t)i*APITCH + NA + 1];
  }
  __syncthreads();

  for (int bp = NPAN-1; bp >= 0; --bp){
    const int k0 = bp*NB;
    const int nb = (NA - k0 < NB) ? (NA - k0) : NB;

    for (int idx = tid; idx < nb*nb; idx += 512){
      int r = idx / nb, c = idx - r*nb;
      u11[r][c] = Ab[(size_t)(k0+r)*APITCH + k0 + c];
    }
    __syncthreads();

    if (wid == 0){
      int j = lane >> 1, ch = lane & 1;
      float tval = (j < nb) ? t2[k0+j][ch] : 0.0f;
      for (int k = nb-1; k >= 0; --k){
        float tk = __shfl(tval, 2*k + ch);
        float xk = tk / u11[k][k];
        if (j <  k) tval = fmaf(-u11[j][k], xk, tval);
        if (j == k) tval = xk;
      }
      if (j < nb) xs[k0+j][ch] = tval;
    }
    __syncthreads();

    if (nb == NB){
      const int q = tid & 7;
      for (int base = 0; base < k0; base += 64){
        const int i = base + (tid >> 3);
        float px = 0.0f, py = 0.0f;
        if (i < k0){
          float4 v = *(const float4*)(Ab + (size_t)i*APITCH + k0 + 4*q);
          px = v.x*xs[k0+4*q+0][0] + v.y*xs[k0+4*q+1][0]
             + v.z*xs[k0+4*q+2][0] + v.w*xs[k0+4*q+3][0];
          py = v.x*xs[k0+4*q+0][1] + v.y*xs[k0+4*q+1][1]
             + v.z*xs[k0+4*q+2][1] + v.w*xs[k0+4*q+3][1];
        }
        px += __shfl_xor(px, 1); px += __shfl_xor(px, 2); px += __shfl_xor(px, 4);
        py += __shfl_xor(py, 1); py += __shfl_xor(py, 2); py += __shfl_xor(py, 4);
        if (q == 0 && i < k0){
          t2[i][0] -= px;
          t2[i][1] -= py;
        }
      }
    } else {
      for (int i = tid; i < k0; i += 512){
        float s0 = 0.0f, s1 = 0.0f;
        #pragma unroll
        for (int m = 0; m < 3; ++m){
          float u = Ab[(size_t)i*APITCH + k0 + m];
          s0 = fmaf(u, xs[k0+m][0], s0);
          s1 = fmaf(u, xs[k0+m][1], s1);
        }
        t2[i][0] -= s0;
        t2[i][1] -= s1;
      }
    }
    __syncthreads();
  }

  for (int i = tid; i < NA; i += 512){
    wv[((size_t)b*NA + i)*2 + 0] = xs[i][0];
    wv[((size_t)b*NA + i)*2 + 1] = xs[i][1];
  }
}

// ---------------------------------------------------------------------------
// Kernel 5: evaluate the warp (r10-proven: PY=4, v_sqrt_f32, float4 LDS).
// ---------------------------------------------------------------------------
__global__ __launch_bounds__(256) void eval_kernel(const float* __restrict__ src,
                                                   const float* __restrict__ wv,
                                                   float* __restrict__ out){
  const int b  = blockIdx.x >> 6;          // 8 batches x 64 y-groups
  const int yg = blockIdx.x & 63;
  const int xi = threadIdx.x;
  __shared__ float4 cw[NCTRL];             // (sx, sy, wx, wy)
  const float* sb = src + b*NCTRL*2;
  const float* wb = wv + (size_t)b*NA*2;
  {
    float2 sv = ((const float2*)sb)[xi];
    float2 wv2 = ((const float2*)wb)[xi];
    cw[xi] = make_float4(sv.x, sv.y, wv2.x, wv2.y);
  }
  __syncthreads();

  const float step = 2.0f/255.0f;
  const float gx = -1.0f + step*(float)xi;
  const float w0x = wb[512], w1x = wb[514], w2x = wb[516];
  const float w0y = wb[513], w1y = wb[515], w2y = wb[517];

  float gy[PY], ax[PY], ay[PY];
  #pragma unroll
  for (int p = 0; p < PY; ++p){
    gy[p] = -1.0f + step*(float)(yg*PY + p);
    ax[p] = w0x + w1x*gx + w2x*gy[p];
    ay[p] = w0y + w1y*gx + w2y*gy[p];
  }

  #pragma unroll 4
  for (int j = 0; j < NCTRL; ++j){
    float4 c = cw[j];
    float dx = gx - c.x;
    float dx2 = dx*dx;
    #pragma unroll
    for (int p = 0; p < PY; ++p){
      float dy = gy[p] - c.y;
      float r = __builtin_amdgcn_sqrtf(fmaf(dy, dy, dx2));
      ax[p] = fmaf(r, c.z, ax[p]);
      ay[p] = fmaf(r, c.w, ay[p]);
    }
  }

  const int y0 = yg*PY;
  #pragma unroll
  for (int p = 0; p < PY; ++p){
    out[((size_t)(b*2    )*SGRID + y0 + p)*SGRID + xi] = ax[p];
    out[((size_t)(b*2 + 1)*SGRID + y0 + p)*SGRID + xi] = ay[p];
  }
}

// ---------------------------------------------------------------------------
extern "C" void kernel_launch(void* const* d_in, const int* in_sizes, int n_in,
                              void* d_out, int out_size, void* d_ws, size_t ws_size,
                              hipStream_t stream) {
  const float* src = (const float*)d_in[0];
  const float* dst = (const float*)d_in[1];
  float* out = (float*)d_out;

  const size_t matElems = (size_t)BATCH*NA*APITCH;
  float* A     = (float*)d_ws;
  float* wv    = A + matElems;
  int*   permb = (int*)(wv + (size_t)BATCH*NA*2);

  build_kernel<<<BATCH*13, 256, 0, stream>>>(src, dst, A);
  panel0_kernel<<<BATCH, 320, 0, stream>>>(A, permb);

  // p = 0..6: update + lookahead of panel p+1 (width 32)
  for (int p = 0; p <= 6; ++p){
    const int k0 = p*NB;
    const int tc = NAUG - (k0 + NB);
    const int sb = (tc + 31) >> 5;
    update_kernel<true, NB><<<BATCH*sb, 256, 0, stream>>>(A, permb, k0, p, sb,
                                                          NB, NB, NB);
  }
  // p = 7: update (1 strip) + lookahead of the 5-wide tail block
  // (3 panel cols + 2 rhs; engine eliminates rhs via its shift updates)
  update_kernel<true, 8><<<BATCH, 256, 0, stream>>>(A, permb, 7*NB, 7, 1,
                                                    3, 5, 5);

  backsub_kernel<<<BATCH, 512, 0, stream>>>(A, wv);
  eval_kernel<<<BATCH*(SGRID/PY), 256, 0, stream>>>(src, wv, out);
}